// Round 10
// baseline (184.190 us; speedup 1.0000x reference)
//
#include <hip/hip_runtime.h>
#include <hip/hip_bf16.h>
#include <math.h>

#define BB 8
#define CC 384
#define NT 1024
#define NHEAD 8
#define HD 48
#define HIDDEN 192
#define THREEC 1152

typedef short short8 __attribute__((ext_vector_type(8)));
typedef short short4v __attribute__((ext_vector_type(4)));
typedef float f32x4 __attribute__((ext_vector_type(4)));
typedef unsigned int uint2v __attribute__((ext_vector_type(2)));
typedef unsigned int uint4v __attribute__((ext_vector_type(4)));

static __device__ __forceinline__ short bf16bits(float v) {
  __hip_bfloat16 h = __float2bfloat16(v);
  return *(short*)&h;
}
// pack two fp32 -> two bf16 (round-half-up) in 3 ops via v_perm_b32
static __device__ __forceinline__ unsigned pk2(float a, float b) {
  return __builtin_amdgcn_perm(__float_as_uint(b) + 0x8000u,
                               __float_as_uint(a) + 0x8000u, 0x07060302u);
}
// async global->LDS DMA, 16B per lane; LDS dest = base + lane*16
static __device__ __forceinline__ void lds_dma16(const void* g, void* l) {
  __builtin_amdgcn_global_load_lds((const __attribute__((address_space(1))) unsigned*)g,
                                   (__attribute__((address_space(3))) unsigned*)l, 16, 0, 0);
}
// explicit full drain (vmcnt/lgkmcnt/expcnt = 0) — belt-and-braces before barriers
static __device__ __forceinline__ void drain_all() { __builtin_amdgcn_s_waitcnt(0); }

// ---------------- fused prep: x/wq/wp transposes + bias table ----------------
__global__ __launch_bounds__(256) void k_prep(
    const float* __restrict__ x, const float* __restrict__ qkv_w,
    const float* __restrict__ proj_w,
    const float* __restrict__ w1, const float* __restrict__ b1,
    const float* __restrict__ w2, const float* __restrict__ b2,
    __hip_bfloat16* __restrict__ xt, __hip_bfloat16* __restrict__ wtq,
    __hip_bfloat16* __restrict__ wtp, float* __restrict__ tab) {
  const int bid = blockIdx.x;
  const int tid = threadIdx.x;
  if (bid >= 3648) {  // ---- bias table ----
    int g = (bid - 3648) * 256 + tid;
    int p = g >> 3, jc = g & 7;
    if (p >= 63 * 63) return;
    float rh = (float)(p / 63 - 31) * (1.0f / 31.0f);
    float rw = (float)(p % 63 - 31) * (1.0f / 31.0f);
    float acc[8] = {0.f, 0.f, 0.f, 0.f, 0.f, 0.f, 0.f, 0.f};
    const int j0 = jc * 24;
#pragma unroll 4
    for (int j = j0; j < j0 + 24; j++) {
      float pre = fmaf(rh, w1[j], fmaf(rw, w1[HIDDEN + j], b1[j]));
      float gl = 0.5f * pre * (1.0f + erff(pre * 0.70710678118654752f));
#pragma unroll
      for (int h = 0; h < 8; h++) acc[h] = fmaf(gl, w2[j * 8 + h], acc[h]);
    }
#pragma unroll
    for (int msk = 1; msk <= 4; msk <<= 1)
#pragma unroll
      for (int h = 0; h < 8; h++) acc[h] += __shfl_xor(acc[h], msk);
    if (jc == 0) {
#pragma unroll
      for (int h = 0; h < 8; h++)
        tab[h * 3969 + p] = (acc[h] + b2[h]) * 1.4426950408889634f;
    }
    return;
  }
  const float* src;
  __hip_bfloat16* dst;
  int R, C, r0, c0;
  if (bid < 3072) {
    int zi = bid / 384, rem = bid % 384;
    R = 384; C = 1024;
    r0 = (rem / 32) * 32; c0 = (rem % 32) * 32;
    src = x + (size_t)zi * R * C;
    dst = xt + (size_t)zi * R * C;
  } else if (bid < 3504) {
    int i = bid - 3072;
    R = 384; C = 1152;
    r0 = (i / 36) * 32; c0 = (i % 36) * 32;
    src = qkv_w; dst = wtq;
  } else {
    int i = bid - 3504;
    R = 384; C = 384;
    r0 = (i / 12) * 32; c0 = (i % 12) * 32;
    src = proj_w; dst = wtp;
  }
  __shared__ float t[32][33];
#pragma unroll
  for (int e = 0; e < 4; e++) {
    int i = tid + e * 256;
    int r = i >> 5, c = i & 31;
    t[r][c] = src[(size_t)(r0 + r) * C + c0 + c];
  }
  __syncthreads();
#pragma unroll
  for (int e = 0; e < 4; e++) {
    int i = tid + e * 256;
    int c = i >> 5, r = i & 31;
    dst[(size_t)(c0 + c) * R + r0 + r] = __float2bfloat16(t[r][c]);
  }
}

// ---------------- QKV GEMM: 128x128 tile, swizzled DMA, coalesced epilogue ----------------
__global__ __launch_bounds__(256) void k_qkv_mfma(
    const __hip_bfloat16* __restrict__ xt,   // [8192][384]
    const __hip_bfloat16* __restrict__ wtq,  // [1152][384]
    const float* __restrict__ qkv_b,
    __hip_bfloat16* __restrict__ Qb,  // [64][1024][64]
    __hip_bfloat16* __restrict__ Kb,  // [64][1024][64]
    __hip_bfloat16* __restrict__ Vt)  // [64][48][1024]
{
  __shared__ __align__(16) char smem[34816];
  short* As = (short*)smem;            // [128][64] swizzled
  short* Bs = (short*)(smem + 16384);  // [128][64] swizzled
  float* Vf = (float*)smem;            // epilogue restage
  const int n0 = blockIdx.x * 128;  // out-channel tile; 0-2 Q, 3-5 K, 6-8 V
  const int m0 = blockIdx.y * 128;  // token tile
  const int tid = threadIdx.x;
  const int wv = tid >> 6, lane = tid & 63, quad = lane >> 4, lq = lane & 15;
  const int msub = (wv >> 1) * 64, nsub = (wv & 1) * 64;
  const int lrow = lane >> 3;
  const int gsw = ((lane & 7) ^ lrow) * 8;
  const int sw0 = (quad ^ (lq & 7)) * 8;
  const int sw1 = sw0 ^ 32;
  f32x4 acc[4][4];
#pragma unroll
  for (int mt = 0; mt < 4; mt++)
#pragma unroll
    for (int nt = 0; nt < 4; nt++) acc[mt][nt] = (f32x4){0.f, 0.f, 0.f, 0.f};
  for (int kk = 0; kk < CC; kk += 64) {
    drain_all();
    __syncthreads();  // seal prev frag reads before overwriting As/Bs
    for (int c = wv; c < 32; c += 4) {
      if (c < 16)
        lds_dma16((const short*)xt + (size_t)(m0 + c * 8 + lrow) * 384 + kk + gsw,
                  smem + c * 1024);
      else
        lds_dma16((const short*)wtq + (size_t)(n0 + (c - 16) * 8 + lrow) * 384 + kk + gsw,
                  smem + 16384 + (c - 16) * 1024);
    }
    drain_all();      // explicit vmcnt(0): DMA landed
    __syncthreads();  // tiles visible to all waves
#pragma unroll
    for (int ks = 0; ks < 2; ks++) {
      const int sws = ks ? sw1 : sw0;
      short8 af[4], bf[4];
#pragma unroll
      for (int t = 0; t < 4; t++) {
        af[t] = *(const short8*)(As + (msub + t * 16 + lq) * 64 + sws);
        bf[t] = *(const short8*)(Bs + (nsub + t * 16 + lq) * 64 + sws);
      }
#pragma unroll
      for (int mt = 0; mt < 4; mt++)
#pragma unroll
        for (int nt = 0; nt < 4; nt++)
          acc[mt][nt] = __builtin_amdgcn_mfma_f32_16x16x32_bf16(af[mt], bf[nt], acc[mt][nt], 0, 0, 0);
    }
  }
  const float qscale = 0.14433756729740643f * 1.4426950408889634f;  // 48^-.5 * log2e
  const float sc = (n0 < 384) ? qscale : 1.0f;
  const int bb = m0 >> 10;
  const int isV = n0 >= 768;
#pragma unroll
  for (int p = 0; p < 2; p++) {
    drain_all();
    __syncthreads();  // seal prior LDS reads (frag reads / phase-0 reads)
    if ((wv & 1) == p) {
      if (isV) {  // Vf[ch][132]
#pragma unroll
        for (int nt = 0; nt < 4; nt++) {
          float bias = qkv_b[n0 + p * 64 + nt * 16 + lq];
#pragma unroll
          for (int mt = 0; mt < 4; mt++)
#pragma unroll
            for (int r = 0; r < 4; r++)
              Vf[(nt * 16 + lq) * 132 + msub + mt * 16 + quad * 4 + r] = acc[mt][nt][r] + bias;
        }
      } else {  // Vf[token][68]
#pragma unroll
        for (int nt = 0; nt < 4; nt++) {
          float bias = qkv_b[n0 + p * 64 + nt * 16 + lq];
#pragma unroll
          for (int mt = 0; mt < 4; mt++)
#pragma unroll
            for (int r = 0; r < 4; r++)
              Vf[(msub + mt * 16 + quad * 4 + r) * 68 + nt * 16 + lq] =
                  (acc[mt][nt][r] + bias) * sc;
        }
      }
    }
    drain_all();
    __syncthreads();  // phase-p data visible
    if (isV) {
#pragma unroll
      for (int e = 0; e < 4; e++) {
        int i = tid + e * 256;  // 1024 items: 64 ch x 16 token-chunks
        int ch = i >> 4, tk = (i & 15) * 8;
        int cg = n0 - 768 + p * 64 + ch;
        int head = cg / 48, d = cg - head * 48;
        const float* s8 = Vf + ch * 132 + tk;
        f32x4 a = *(const f32x4*)s8, b2 = *(const f32x4*)(s8 + 4);
        uint4v o;
        o[0] = pk2(a[0], a[1]); o[1] = pk2(a[2], a[3]);
        o[2] = pk2(b2[0], b2[1]); o[3] = pk2(b2[2], b2[3]);
        *(uint4v*)((short*)Vt + ((size_t)(bb * 8 + head) * 48 + d) * 1024 + (m0 & 1023) + tk) = o;
      }
    } else {
      const int which = n0 >= 384;
      short* Out = which ? (short*)Kb : (short*)Qb;
#pragma unroll
      for (int e = 0; e < 4; e++) {
        int i = tid + e * 256;  // 1024 items: 128 tokens x 8 chan-chunks
        int token = i >> 3, c8 = (i & 7) * 8;
        int cg = (n0 - which * 384) + p * 64 + c8;
        int head = cg / 48, d0 = cg - head * 48;  // chunk never crosses head (48%8==0)
        const float* s8 = Vf + token * 68 + c8;
        f32x4 a = *(const f32x4*)s8, b2 = *(const f32x4*)(s8 + 4);
        uint4v o;
        o[0] = pk2(a[0], a[1]); o[1] = pk2(a[2], a[3]);
        o[2] = pk2(b2[0], b2[1]); o[3] = pk2(b2[2], b2[3]);
        short* dst = Out + (((size_t)(bb * 8 + head) << 10) + (m0 & 1023) + token) * 64 + d0;
        *(uint4v*)dst = o;
        if (d0 == 40) {  // owner of last chunk writes the d=48..63 zero pad
          uint4v z = (uint4v){0u, 0u, 0u, 0u};
          *(uint4v*)(dst + 8) = z;
          *(uint4v*)(dst + 16) = z;
        }
      }
    }
  }
}

// ---------------- fused flash attention (R8-proven version, verbatim) ----------------
// S^T + swizzled dbuf DMA + NO-MAX softmax + per-iter 1KB bias-strip DMA + ones-reg L
#define K0_OFF 0       // K buf0: 8192
#define K1_OFF 8192    // K buf1: 8192
#define V0_OFF 16384   // V buf0: 6144
#define V1_OFF 22528   // V buf1: 6144
#define TR_OFF 28672   // tab strips: 2 x 1024
#define PS_OFF 30720   // 64 x 72 shorts (9216)
#define SMEM_SZ 39936
__global__ __launch_bounds__(256, 4) void k_flash(
    const __hip_bfloat16* __restrict__ Qb, const __hip_bfloat16* __restrict__ Kb,
    const __hip_bfloat16* __restrict__ Vt, const float* __restrict__ tab,
    __hip_bfloat16* __restrict__ ATb)  // [8][1024][384]
{
  __shared__ __align__(16) char smem[SMEM_SZ];
  short* Ps_l = (short*)(smem + PS_OFF);
  float* Os = (float*)smem;

  const int tid = threadIdx.x;
  const int wv = tid >> 6, lane = tid & 63, quad = lane >> 4, lq = lane & 15;
  const int bh = blockIdx.x;
  const int q0 = blockIdx.y * 64;
  const int b = bh >> 3, h = bh & 7;
  const int inr0 = q0 >> 5;

  const int nrow = q0 + wv * 16 + lq;
  const int jnr = nrow & 31;
  const int rloc = (nrow >> 5) - inr0 + 1;  // in {1, 2}
  const int tbase = rloc * 63 + jnr + 31 - 4 * quad;

  short8 qf0, qf1;
  {
    const short* qp = (const short*)Qb + ((size_t)(bh << 10) + nrow) * 64;
    qf0 = *(const short8*)(qp + quad * 8);
    qf1 = *(const short8*)(qp + 32 + quad * 8);
  }
  short8 onesv;
#pragma unroll
  for (int j = 0; j < 8; j++) onesv[j] = (short)0x3F80;  // bf16(1.0)

  f32x4 O[4];  // O[3] = L accumulator
#pragma unroll
  for (int dt = 0; dt < 4; dt++) O[dt] = (f32x4){0.f, 0.f, 0.f, 0.f};

  const short* kgp = (const short*)Kb + ((size_t)(bh << 10)) * 64;
  const short* vgp = (const short*)Vt + (size_t)bh * 48 * 1024;
  const float* tabg = tab + h * 3969;
  const int lrow = lane >> 3;
  const int gsw = ((lane & 7) ^ lrow) * 8;
  const int sw0 = (quad ^ (lq & 7)) * 8;
  const int sw1 = sw0 ^ 32;

  // prologue: DMA tile 0 + tab strip 0 (rows inr0+30 ..) -> buf0
  for (int c = wv; c < 15; c += 4) {
    if (c < 8)
      lds_dma16(kgp + (size_t)(c * 8 + lrow) * 64 + gsw, smem + K0_OFF + c * 1024);
    else if (c < 14)
      lds_dma16(vgp + (size_t)((c - 8) * 8 + lrow) * 1024 + gsw,
                smem + V0_OFF + (c - 8) * 1024);
    else
      lds_dma16(tabg + (inr0 + 30) * 63 + lane * 4, smem + TR_OFF);
  }

  for (int it = 0; it < 16; it++) {
    const int m0 = it * 64;
    const int buf = it & 1;
    drain_all();      // explicit vmcnt(0): tile-it DMA landed
    __syncthreads();
    if (it < 15) {    // prefetch tile it+1 into the other buffer
      const int nbuf = buf ^ 1;
      const int mn = m0 + 64;
      for (int c = wv; c < 15; c += 4) {
        if (c < 8)
          lds_dma16(kgp + (size_t)(mn + c * 8 + lrow) * 64 + gsw,
                    smem + K0_OFF + nbuf * 8192 + c * 1024);
        else if (c < 14)
          lds_dma16(vgp + (size_t)((c - 8) * 8 + lrow) * 1024 + mn + gsw,
                    smem + V0_OFF + nbuf * 6144 + (c - 8) * 1024);
        else
          lds_dma16(tabg + (inr0 + 28 - 2 * it) * 63 + lane * 4,
                    smem + TR_OFF + nbuf * 1024);
      }
    }
    const short* Kl = (const short*)(smem + K0_OFF + buf * 8192);
    const short* Vl = (const short*)(smem + V0_OFF + buf * 6144);
    const float* Tl = (const float*)(smem + TR_OFF + buf * 1024);

    // S^T = mfma(K-frag, Q-frag) with bias strip as accumulator init
    float s[4][4];
#pragma unroll
    for (int nt = 0; nt < 4; nt++) {
      const float* tn = Tl + tbase - (nt >= 2 ? 63 : 0) - (nt & 1) * 16;
      f32x4 c;
      c[0] = tn[0]; c[1] = tn[-1]; c[2] = tn[-2]; c[3] = tn[-3];
      c = __builtin_amdgcn_mfma_f32_16x16x32_bf16(
          *(const short8*)(Kl + (nt * 16 + lq) * 64 + sw0), qf0, c, 0, 0, 0);
      c = __builtin_amdgcn_mfma_f32_16x16x32_bf16(
          *(const short8*)(Kl + (nt * 16 + lq) * 64 + sw1), qf1, c, 0, 0, 0);
#pragma unroll
      for (int r = 0; r < 4; r++) s[nt][r] = c[r];
    }
    // no-max softmax: exp2 directly (shift-invariant; args bounded ~|8|)
#pragma unroll
    for (int nt = 0; nt < 4; nt++)
#pragma unroll
      for (int r = 0; r < 4; r++) s[nt][r] = exp2f(s[nt][r]);
    // P^T -> LDS (own-wave round trip, padded region: no barrier)
#pragma unroll
    for (int nt = 0; nt < 4; nt++) {
      uint2v pw;
      pw[0] = pk2(s[nt][0], s[nt][1]);
      pw[1] = pk2(s[nt][2], s[nt][3]);
      *(uint2v*)(Ps_l + (wv * 16 + lq) * 72 + nt * 16 + quad * 4) = pw;
    }
    // O^T += mfma(V^T-frag, P^T-frag); L via register-ones A operand
#pragma unroll
    for (int ks = 0; ks < 2; ks++) {
      short8 pf = *(const short8*)(Ps_l + (wv * 16 + lq) * 72 + ks * 32 + quad * 8);
      const int sws = ks ? sw1 : sw0;
#pragma unroll
      for (int dt = 0; dt < 3; dt++)
        O[dt] = __builtin_amdgcn_mfma_f32_16x16x32_bf16(
            *(const short8*)(Vl + (dt * 16 + lq) * 64 + sws), pf, O[dt], 0, 0, 0);
      O[3] = __builtin_amdgcn_mfma_f32_16x16x32_bf16(onesv, pf, O[3], 0, 0, 0);
    }
  }
  float inv = 1.0f / O[3][0];  // L(q = wv*16+lq), no shuffle
  drain_all();
  __syncthreads();             // all PV reads done before Os aliases buffers
#pragma unroll
  for (int dt = 0; dt < 3; dt++)
#pragma unroll
    for (int r = 0; r < 4; r++)
      Os[(wv * 16 + lq) * 52 + dt * 16 + quad * 4 + r] = O[dt][r] * inv;
  drain_all();
  __syncthreads();
  {
    int row = tid >> 2, cg = (tid & 3) * 12;
    const float* src = Os + row * 52 + cg;
    short outp[12];
#pragma unroll
    for (int k = 0; k < 12; k++) outp[k] = bf16bits(src[k]);
    short* dst = (short*)ATb + ((size_t)(b << 10) + q0 + row) * 384 + h * 48 + cg;
    *(short4v*)dst = *(short4v*)outp;
    *(short4v*)(dst + 4) = *(short4v*)(outp + 4);
    *(short4v*)(dst + 8) = *(short4v*)(outp + 8);
  }
}

// ---------------- proj GEMM: 128x128 tile, swizzled DMA ----------------
__global__ __launch_bounds__(256) void k_proj_mfma(
    const __hip_bfloat16* __restrict__ ATb,  // [8][1024][384]
    const __hip_bfloat16* __restrict__ wtp,  // [384][384] ([cout][cin])
    const float* __restrict__ pb, float* __restrict__ out) {
  __shared__ __align__(16) char smem[32768];
  short* As = (short*)smem;            // wtp rows (c), [128][64]
  short* Bs = (short*)(smem + 16384);  // ATb rows (n), [128][64]
  const int c0 = blockIdx.x * 128;
  const int n0 = blockIdx.y * 128;
  const int b = blockIdx.z;
  const int tid = threadIdx.x;
  const int wv = tid >> 6, lane = tid & 63, quad = lane >> 4, lq = lane & 15;
  const int msub = (wv >> 1) * 64, nsub = (wv & 1) * 64;
  const int lrow = lane >> 3;
  const int gsw = ((lane & 7) ^ lrow) * 8;
  const int sw0 = (quad ^ (lq & 7)) * 8;
  const int sw1 = sw0 ^ 32;
  f32x4 acc[4][4];
#pragma unroll
  for (int mt = 0; mt < 4; mt++)
#pragma unroll
    for (int nt = 0; nt < 4; nt++) acc[mt][nt] = (f32x4){0.f, 0.f, 0.f, 0.f};
  for (int kk = 0; kk < CC; kk += 64) {
    drain_all();
    __syncthreads();
    for (int c = wv; c < 32; c += 4) {
      if (c < 16)
        lds_dma16((const short*)wtp + (size_t)(c0 + c * 8 + lrow) * 384 + kk + gsw,
                  smem + c * 1024);
      else
        lds_dma16((const short*)ATb + ((size_t)(b << 10) + n0 + (c - 16) * 8 + lrow) * 384 + kk + gsw,
                  smem + 16384 + (c - 16) * 1024);
    }
    drain_all();
    __syncthreads();
#pragma unroll
    for (int ks = 0; ks < 2; ks++) {
      const int sws = ks ? sw1 : sw0;
      short8 af[4], bf[4];
#pragma unroll
      for (int t = 0; t < 4; t++) {
        af[t] = *(const short8*)(As + (msub + t * 16 + lq) * 64 + sws);
        bf[t] = *(const short8*)(Bs + (nsub + t * 16 + lq) * 64 + sws);
      }
#pragma unroll
      for (int mt = 0; mt < 4; mt++)
#pragma unroll
        for (int nt = 0; nt < 4; nt++)
          acc[mt][nt] = __builtin_amdgcn_mfma_f32_16x16x32_bf16(af[mt], bf[nt], acc[mt][nt], 0, 0, 0);
    }
  }
#pragma unroll
  for (int mt = 0; mt < 4; mt++)
#pragma unroll
    for (int r = 0; r < 4; r++) {
      int c = c0 + msub + mt * 16 + quad * 4 + r;
      float bc = pb[c];
      float* dst = out + ((size_t)b * 384 + c) * 1024 + n0 + nsub;
#pragma unroll
      for (int nt = 0; nt < 4; nt++) dst[nt * 16 + lq] = acc[mt][nt][r] + bc;
    }
}

extern "C" void kernel_launch(void* const* d_in, const int* in_sizes, int n_in,
                              void* d_out, int out_size, void* d_ws, size_t ws_size,
                              hipStream_t stream) {
  const float* x = (const float*)d_in[0];
  const float* qkv_w = (const float*)d_in[1];
  const float* qkv_b = (const float*)d_in[2];
  const float* proj_w = (const float*)d_in[3];
  const float* proj_b = (const float*)d_in[4];
  const float* w1 = (const float*)d_in[5];
  const float* b1 = (const float*)d_in[6];
  const float* w2 = (const float*)d_in[7];
  const float* b2 = (const float*)d_in[8];
  float* out = (float*)d_out;

  char* w = (char*)d_ws;
  __hip_bfloat16* xt = (__hip_bfloat16*)w;   w += (size_t)8192 * 384 * 2;
  __hip_bfloat16* wtq = (__hip_bfloat16*)w;  w += (size_t)1152 * 384 * 2;
  __hip_bfloat16* wtp = (__hip_bfloat16*)w;  w += (size_t)384 * 384 * 2;
  __hip_bfloat16* Qb = (__hip_bfloat16*)w;   w += (size_t)64 * 1024 * 64 * 2;
  __hip_bfloat16* Kb = (__hip_bfloat16*)w;   w += (size_t)64 * 1024 * 64 * 2;
  __hip_bfloat16* Vt = (__hip_bfloat16*)w;   w += (size_t)64 * 48 * 1024 * 2;
  __hip_bfloat16* ATb = (__hip_bfloat16*)w;  w += (size_t)8192 * 384 * 2;
  float* tab = (float*)w;                    w += (size_t)8 * 3969 * 4 + 2048;  // +2KB DMA slack

  k_prep<<<dim3(3773), dim3(256), 0, stream>>>(x, qkv_w, proj_w, w1, b1, w2, b2,
                                               xt, wtq, wtp, tab);
  k_qkv_mfma<<<dim3(9, 64), dim3(256), 0, stream>>>(xt, wtq, qkv_b, Qb, Kb, Vt);
  k_flash<<<dim3(64, 16), dim3(256), 0, stream>>>(Qb, Kb, Vt, tab, ATb);
  k_proj_mfma<<<dim3(3, 8, 8), dim3(256), 0, stream>>>(ATb, wtp, proj_b, out);
}